// Round 1
// baseline (266.117 us; speedup 1.0000x reference)
//
#include <hip/hip_runtime.h>

#define L_SEQ   4096
#define BATCH   2
#define DMODEL  1024
#define HEADS   16
#define DKH     64
#define NBF     16
#define CHUNK   64
#define NCHUNK  64          // L_SEQ / CHUNK
#define NCHAIN  32          // BATCH * HEADS
#define STATE_SZ 1040       // NBF*DKH + NBF
#define EPSF    1e-6f

typedef __attribute__((ext_vector_type(8))) __bf16 bf16x8;
typedef __attribute__((ext_vector_type(4))) float  floatx4;

__device__ __forceinline__ unsigned short f2bf(float x) {
  unsigned u = __builtin_bit_cast(unsigned, x);
  u += 0x7fffu + ((u >> 16) & 1u);
  return (unsigned short)(u >> 16);
}
__device__ __forceinline__ float bf2f(unsigned short u) {
  return __builtin_bit_cast(float, ((unsigned)u) << 16);
}

// ---------------- cast f32 -> bf16 (vectorized) ----------------
__global__ __launch_bounds__(256) void cast_kernel(const float* __restrict__ in,
                                                   unsigned short* __restrict__ out, int n4) {
  int i = blockIdx.x * 256 + threadIdx.x;
  if (i >= n4) return;
  float4 v = ((const float4*)in)[i];
  ushort4 o;
  o.x = f2bf(v.x); o.y = f2bf(v.y); o.z = f2bf(v.z); o.w = f2bf(v.w);
  ((ushort4*)out)[i] = o;
}

// ---------------- bf16 MFMA GEMM: C = A(MxK) * Bt(NxK)^T ----------------
__device__ __forceinline__ void store_c(float* p, float v) { *p = v; }
__device__ __forceinline__ void store_c(unsigned short* p, float v) { *p = f2bf(v); }

template <typename OutT>
__global__ __launch_bounds__(256) void gemm_bt(const unsigned short* __restrict__ A,
                                               const unsigned short* __restrict__ Bt,
                                               OutT* __restrict__ C,
                                               int M, int N, int K) {
  __shared__ unsigned short As[128 * 32];
  __shared__ unsigned short Bs[128 * 32];
  const int tid  = threadIdx.x;
  const int wave = tid >> 6, lane = tid & 63;
  const int mt = blockIdx.y << 7, nt = blockIdx.x << 7;
  const int wm = (wave >> 1) << 6, wn = (wave & 1) << 6;
  const int r16 = lane & 15, kg = lane >> 4;

  floatx4 acc[4][4];
#pragma unroll
  for (int m = 0; m < 4; ++m)
#pragma unroll
    for (int n = 0; n < 4; ++n) acc[m][n] = floatx4{0.f, 0.f, 0.f, 0.f};

  const int ldrow = wave * 16 + (lane >> 2);   // row within tile for staging load 0
  const int ldcol = (lane & 3) << 3;           // element col within BK
  const unsigned short* aG = A  + (size_t)(mt + ldrow) * K + ldcol;
  const unsigned short* bG = Bt + (size_t)(nt + ldrow) * K + ldcol;
  char* aL = (char*)As + wave * 1024;
  char* bL = (char*)Bs + wave * 1024;

  for (int kt = 0; kt < K; kt += 32) {
    __builtin_amdgcn_global_load_lds((const __attribute__((address_space(1))) void*)(aG + kt),
                                     (__attribute__((address_space(3))) void*)aL, 16, 0, 0);
    __builtin_amdgcn_global_load_lds((const __attribute__((address_space(1))) void*)(aG + (size_t)64 * K + kt),
                                     (__attribute__((address_space(3))) void*)(aL + 4096), 16, 0, 0);
    __builtin_amdgcn_global_load_lds((const __attribute__((address_space(1))) void*)(bG + kt),
                                     (__attribute__((address_space(3))) void*)bL, 16, 0, 0);
    __builtin_amdgcn_global_load_lds((const __attribute__((address_space(1))) void*)(bG + (size_t)64 * K + kt),
                                     (__attribute__((address_space(3))) void*)(bL + 4096), 16, 0, 0);
    __syncthreads();

    bf16x8 af[4], bfr[4];
#pragma unroll
    for (int m = 0; m < 4; ++m)
      af[m] = *(const bf16x8*)&As[(wm + m * 16 + r16) * 32 + kg * 8];
#pragma unroll
    for (int n = 0; n < 4; ++n)
      bfr[n] = *(const bf16x8*)&Bs[(wn + n * 16 + r16) * 32 + kg * 8];
#pragma unroll
    for (int m = 0; m < 4; ++m)
#pragma unroll
      for (int n = 0; n < 4; ++n)
        acc[m][n] = __builtin_amdgcn_mfma_f32_16x16x32_bf16(af[m], bfr[n], acc[m][n], 0, 0, 0);
    __syncthreads();
  }

#pragma unroll
  for (int m = 0; m < 4; ++m) {
    const int row0 = mt + wm + m * 16 + kg * 4;
#pragma unroll
    for (int n = 0; n < 4; ++n) {
      const int col = nt + wn + n * 16 + r16;
#pragma unroll
      for (int r = 0; r < 4; ++r)
        store_c(&C[(size_t)(row0 + r) * N + col], acc[m][n][r]);
    }
  }
}

// ---------------- feature map: xp = normalize(exp(-0.5*(xh . omega^T)^2)) ----------------
// one block per (b,l); 256 threads = 16 heads x 16 features
// writes TRANSPOSED layout xp_t[(b*H + h)*L + l][f] for scan-friendly access
__global__ __launch_bounds__(256) void feature_kernel(const unsigned short* __restrict__ xh,
                                                      const float* __restrict__ omega,
                                                      float* __restrict__ xp_t) {
  __shared__ float om_s[NBF * 65];
  __shared__ float xr_s[HEADS * 65];
  const int tid = threadIdx.x;
  const int bl = blockIdx.x;  // b*L + l
  for (int i = tid; i < NBF * DKH; i += 256) om_s[(i >> 6) * 65 + (i & 63)] = omega[i];
  const unsigned short* xrow = xh + (size_t)bl * DMODEL;
  for (int i = tid; i < DMODEL; i += 256) xr_s[(i >> 6) * 65 + (i & 63)] = bf2f(xrow[i]);
  __syncthreads();
  const int h = tid >> 4, f = tid & 15;
  const float* xr  = &xr_s[h * 65];
  const float* omf = &om_s[f * 65];
  float x = 0.f;
#pragma unroll
  for (int d = 0; d < DKH; ++d) x += xr[d] * omf[d];
  float p = __expf(-0.5f * x * x);
  float s = p;
  s += __shfl_xor(s, 1);
  s += __shfl_xor(s, 2);
  s += __shfl_xor(s, 4);
  s += __shfl_xor(s, 8);
  p = p / (s + EPSF);
  const int b = bl >> 12, l = bl & 4095;
  xp_t[(((size_t)(b * HEADS + h)) * L_SEQ + l) * NBF + f] = p;
}

// ---------------- scan phase A: per-chunk local sums ----------------
// grid: NCHAIN*NCHUNK blocks of 64 threads (thread d owns S[f][d] for all f)
__global__ __launch_bounds__(64) void scan_chunk_sum(const float* __restrict__ kp_t,
                                                     const unsigned short* __restrict__ vh,
                                                     float* __restrict__ Sws) {
  const int c = blockIdx.x & (NCHUNK - 1);
  const int chain = blockIdx.x >> 6;
  const int b = chain >> 4, h = chain & 15;
  const int d = threadIdx.x;
  __shared__ float kp_s[CHUNK * NBF];
  const float* kpB = kp_t + ((size_t)chain * L_SEQ + c * CHUNK) * NBF;
  for (int i = 0; i < 16; ++i) kp_s[d + i * 64] = kpB[d + i * 64];
  __syncthreads();
  float S[NBF];
#pragma unroll
  for (int f = 0; f < NBF; ++f) S[f] = 0.f;
  const unsigned short* vB = vh + ((size_t)(b * L_SEQ + c * CHUNK)) * DMODEL + h * DKH + d;
  for (int l = 0; l < CHUNK; ++l) {
    float vv = bf2f(vB[(size_t)l * DMODEL]);
#pragma unroll
    for (int f = 0; f < NBF; ++f) S[f] += kp_s[l * NBF + f] * vv;
  }
  float* out = Sws + ((size_t)chain * NCHUNK + c) * STATE_SZ;
#pragma unroll
  for (int f = 0; f < NBF; ++f) out[f * 64 + d] = S[f];
  if (d < NBF) {
    float ks = 0.f;
    for (int l = 0; l < CHUNK; ++l) ks += kp_s[l * NBF + d];
    out[1024 + d] = ks;
  }
}

// ---------------- scan phase B: exclusive scan over chunks (in place) ----------------
__global__ __launch_bounds__(256) void scan_chunks(float* __restrict__ Sws) {
  const int chain = blockIdx.x;
  for (int e = threadIdx.x; e < STATE_SZ; e += 256) {
    float acc = 0.f;
    float* p = Sws + (size_t)chain * NCHUNK * STATE_SZ + e;
    for (int c = 0; c < NCHUNK; ++c) {
      float v = p[(size_t)c * STATE_SZ];
      p[(size_t)c * STATE_SZ] = acc;
      acc += v;
    }
  }
}

// ---------------- scan phase C: apply within chunk, write attn out (bf16) ----------------
__global__ __launch_bounds__(64) void scan_apply(const float* __restrict__ qp_t,
                                                 const float* __restrict__ kp_t,
                                                 const unsigned short* __restrict__ vh,
                                                 const float* __restrict__ Sws,
                                                 unsigned short* __restrict__ attn) {
  const int c = blockIdx.x & (NCHUNK - 1);
  const int chain = blockIdx.x >> 6;
  const int b = chain >> 4, h = chain & 15;
  const int d = threadIdx.x;
  __shared__ float kp_s[CHUNK * NBF];
  __shared__ float qp_s[CHUNK * NBF];
  {
    const float* kpB = kp_t + ((size_t)chain * L_SEQ + c * CHUNK) * NBF;
    const float* qpB = qp_t + ((size_t)chain * L_SEQ + c * CHUNK) * NBF;
    for (int i = 0; i < 16; ++i) {
      kp_s[d + i * 64] = kpB[d + i * 64];
      qp_s[d + i * 64] = qpB[d + i * 64];
    }
  }
  __syncthreads();
  const float* st = Sws + ((size_t)chain * NCHUNK + c) * STATE_SZ;
  float S[NBF], kc[NBF];
#pragma unroll
  for (int f = 0; f < NBF; ++f) S[f] = st[f * 64 + d];
#pragma unroll
  for (int f = 0; f < NBF; ++f) kc[f] = st[1024 + f];
  const unsigned short* vB = vh + ((size_t)(b * L_SEQ + c * CHUNK)) * DMODEL + h * DKH + d;
  unsigned short* oB = attn + ((size_t)(b * L_SEQ + c * CHUNK)) * DMODEL + h * DKH + d;
  for (int l = 0; l < CHUNK; ++l) {
    float vv = bf2f(vB[(size_t)l * DMODEL]);
    float num = 0.f, den = 0.f;
#pragma unroll
    for (int f = 0; f < NBF; ++f) {
      float kpf = kp_s[l * NBF + f];
      S[f]  += kpf * vv;
      kc[f] += kpf;
      float qpf = qp_s[l * NBF + f];
      num += qpf * S[f];
      den += qpf * kc[f];
    }
    oB[(size_t)l * DMODEL] = f2bf(num / (den + EPSF));
  }
}

// ---------------- host launch ----------------
extern "C" void kernel_launch(void* const* d_in, const int* in_sizes, int n_in,
                              void* d_out, int out_size, void* d_ws, size_t ws_size,
                              hipStream_t stream) {
  const float* q   = (const float*)d_in[0];
  const float* k   = (const float*)d_in[1];
  const float* v   = (const float*)d_in[2];
  const float* w_q = (const float*)d_in[3];
  const float* w_k = (const float*)d_in[4];
  const float* w_v = (const float*)d_in[5];
  const float* w_o = (const float*)d_in[6];
  const float* omega = (const float*)d_in[7];
  float* out = (float*)d_out;

  constexpr size_t NQ = (size_t)BATCH * L_SEQ * DMODEL;      // 8388608
  constexpr size_t NW = (size_t)DMODEL * DMODEL;             // 1048576
  constexpr size_t NP = (size_t)BATCH * HEADS * L_SEQ * NBF; // 2097152
  constexpr size_t NS = (size_t)NCHAIN * NCHUNK * STATE_SZ;

  char* ws = (char*)d_ws;
  size_t off = 0;
  auto alc = [&](size_t bytes) { void* p = ws + off; off += (bytes + 255) & ~(size_t)255; return p; };
  unsigned short* qb  = (unsigned short*)alc(NQ * 2);
  unsigned short* kb  = (unsigned short*)alc(NQ * 2);
  unsigned short* vb  = (unsigned short*)alc(NQ * 2);
  unsigned short* wqb = (unsigned short*)alc(NW * 2);
  unsigned short* wkb = (unsigned short*)alc(NW * 2);
  unsigned short* wvb = (unsigned short*)alc(NW * 2);
  unsigned short* wob = (unsigned short*)alc(NW * 2);
  unsigned short* qh  = (unsigned short*)alc(NQ * 2);  // reused for kh
  unsigned short* vh  = (unsigned short*)alc(NQ * 2);
  float* qp  = (float*)alc(NP * 4);
  float* kp  = (float*)alc(NP * 4);
  float* Sws = (float*)alc(NS * 4);
  unsigned short* attn = qb;  // qb is dead after the q-projection GEMM

  cast_kernel<<<(int)(NQ / 4 / 256), 256, 0, stream>>>(q, qb, (int)(NQ / 4));
  cast_kernel<<<(int)(NQ / 4 / 256), 256, 0, stream>>>(k, kb, (int)(NQ / 4));
  cast_kernel<<<(int)(NQ / 4 / 256), 256, 0, stream>>>(v, vb, (int)(NQ / 4));
  cast_kernel<<<(int)(NW / 4 / 256), 256, 0, stream>>>(w_q, wqb, (int)(NW / 4));
  cast_kernel<<<(int)(NW / 4 / 256), 256, 0, stream>>>(w_k, wkb, (int)(NW / 4));
  cast_kernel<<<(int)(NW / 4 / 256), 256, 0, stream>>>(w_v, wvb, (int)(NW / 4));
  cast_kernel<<<(int)(NW / 4 / 256), 256, 0, stream>>>(w_o, wob, (int)(NW / 4));

  dim3 gg(DMODEL / 128, (BATCH * L_SEQ) / 128);  // (8, 64)

  gemm_bt<unsigned short><<<gg, 256, 0, stream>>>(qb, wqb, qh, BATCH * L_SEQ, DMODEL, DMODEL);
  feature_kernel<<<BATCH * L_SEQ, 256, 0, stream>>>(qh, omega, qp);
  gemm_bt<unsigned short><<<gg, 256, 0, stream>>>(kb, wkb, qh, BATCH * L_SEQ, DMODEL, DMODEL);
  feature_kernel<<<BATCH * L_SEQ, 256, 0, stream>>>(qh, omega, kp);
  gemm_bt<unsigned short><<<gg, 256, 0, stream>>>(vb, wvb, vh, BATCH * L_SEQ, DMODEL, DMODEL);

  scan_chunk_sum<<<NCHAIN * NCHUNK, 64, 0, stream>>>(kp, vh, Sws);
  scan_chunks<<<NCHAIN, 256, 0, stream>>>(Sws);
  scan_apply<<<NCHAIN * NCHUNK, 64, 0, stream>>>(qp, kp, vh, Sws, attn);

  gemm_bt<float><<<gg, 256, 0, stream>>>(attn, wob, out, BATCH * L_SEQ, DMODEL, DMODEL);
}

// Round 2
// 211.533 us; speedup vs baseline: 1.2580x; 1.2580x over previous
//
#include <hip/hip_runtime.h>

#define L_SEQ   4096
#define BATCH   2
#define DMODEL  1024
#define HEADS   16
#define DKH     64
#define NBF     16
#define CHUNK   64
#define NCHUNK  64          // L_SEQ / CHUNK
#define NCHAIN  32          // BATCH * HEADS
#define STATE_SZ 1040       // NBF*DKH + NBF
#define EPSF    1e-6f

typedef __attribute__((ext_vector_type(8))) __bf16 bf16x8;
typedef __attribute__((ext_vector_type(4))) float  floatx4;
typedef __attribute__((ext_vector_type(8))) unsigned short ushort8v;

__device__ __forceinline__ unsigned short f2bf(float x) {
  unsigned u = __builtin_bit_cast(unsigned, x);
  u += 0x7fffu + ((u >> 16) & 1u);
  return (unsigned short)(u >> 16);
}
__device__ __forceinline__ float bf2f(unsigned short u) {
  return __builtin_bit_cast(float, ((unsigned)u) << 16);
}

// ---------------- casts f32 -> bf16 (batched, vectorized) ----------------
__global__ __launch_bounds__(256) void cast3(const float* __restrict__ a, const float* __restrict__ b,
                                             const float* __restrict__ c,
                                             unsigned short* __restrict__ oa, unsigned short* __restrict__ ob,
                                             unsigned short* __restrict__ oc, int n4) {
  int i = blockIdx.x * 256 + threadIdx.x;
  if (i >= n4) return;
  int w = blockIdx.y;
  const float* in = (w == 0) ? a : (w == 1) ? b : c;
  unsigned short* out = (w == 0) ? oa : (w == 1) ? ob : oc;
  float4 v = ((const float4*)in)[i];
  ushort4 o;
  o.x = f2bf(v.x); o.y = f2bf(v.y); o.z = f2bf(v.z); o.w = f2bf(v.w);
  ((ushort4*)out)[i] = o;
}

__global__ __launch_bounds__(256) void cast4(const float* __restrict__ a, const float* __restrict__ b,
                                             const float* __restrict__ c, const float* __restrict__ d,
                                             unsigned short* __restrict__ oa, unsigned short* __restrict__ ob,
                                             unsigned short* __restrict__ oc, unsigned short* __restrict__ od,
                                             int n4) {
  int i = blockIdx.x * 256 + threadIdx.x;
  if (i >= n4) return;
  int w = blockIdx.y;
  const float* in = (w == 0) ? a : (w == 1) ? b : (w == 2) ? c : d;
  unsigned short* out = (w == 0) ? oa : (w == 1) ? ob : (w == 2) ? oc : od;
  float4 v = ((const float4*)in)[i];
  ushort4 o;
  o.x = f2bf(v.x); o.y = f2bf(v.y); o.z = f2bf(v.z); o.w = f2bf(v.w);
  ((ushort4*)out)[i] = o;
}

// ---------------- bf16 MFMA GEMM: C = A(MxK) * Bt(NxK)^T ----------------
__device__ __forceinline__ void store_c(float* p, float v) { *p = v; }
__device__ __forceinline__ void store_c(unsigned short* p, float v) { *p = f2bf(v); }

template <typename OutT>
__global__ __launch_bounds__(256) void gemm_bt(const unsigned short* __restrict__ A,
                                               const unsigned short* __restrict__ Bt,
                                               OutT* __restrict__ C,
                                               int M, int N, int K) {
  __shared__ unsigned short As[128 * 32];
  __shared__ unsigned short Bs[128 * 32];
  const int tid  = threadIdx.x;
  const int wave = tid >> 6, lane = tid & 63;
  const int mt = blockIdx.y << 7, nt = blockIdx.x << 7;
  const int wm = (wave >> 1) << 6, wn = (wave & 1) << 6;
  const int r16 = lane & 15, kg = lane >> 4;

  floatx4 acc[4][4];
#pragma unroll
  for (int m = 0; m < 4; ++m)
#pragma unroll
    for (int n = 0; n < 4; ++n) acc[m][n] = floatx4{0.f, 0.f, 0.f, 0.f};

  const int ldrow = wave * 16 + (lane >> 2);
  const int ldcol = (lane & 3) << 3;
  const unsigned short* aG = A  + (size_t)(mt + ldrow) * K + ldcol;
  const unsigned short* bG = Bt + (size_t)(nt + ldrow) * K + ldcol;
  char* aL = (char*)As + wave * 1024;
  char* bL = (char*)Bs + wave * 1024;

  for (int kt = 0; kt < K; kt += 32) {
    __builtin_amdgcn_global_load_lds((const __attribute__((address_space(1))) void*)(aG + kt),
                                     (__attribute__((address_space(3))) void*)aL, 16, 0, 0);
    __builtin_amdgcn_global_load_lds((const __attribute__((address_space(1))) void*)(aG + (size_t)64 * K + kt),
                                     (__attribute__((address_space(3))) void*)(aL + 4096), 16, 0, 0);
    __builtin_amdgcn_global_load_lds((const __attribute__((address_space(1))) void*)(bG + kt),
                                     (__attribute__((address_space(3))) void*)bL, 16, 0, 0);
    __builtin_amdgcn_global_load_lds((const __attribute__((address_space(1))) void*)(bG + (size_t)64 * K + kt),
                                     (__attribute__((address_space(3))) void*)(bL + 4096), 16, 0, 0);
    __syncthreads();

    bf16x8 af[4], bfr[4];
#pragma unroll
    for (int m = 0; m < 4; ++m)
      af[m] = *(const bf16x8*)&As[(wm + m * 16 + r16) * 32 + kg * 8];
#pragma unroll
    for (int n = 0; n < 4; ++n)
      bfr[n] = *(const bf16x8*)&Bs[(wn + n * 16 + r16) * 32 + kg * 8];
#pragma unroll
    for (int m = 0; m < 4; ++m)
#pragma unroll
      for (int n = 0; n < 4; ++n)
        acc[m][n] = __builtin_amdgcn_mfma_f32_16x16x32_bf16(af[m], bfr[n], acc[m][n], 0, 0, 0);
    __syncthreads();
  }

#pragma unroll
  for (int m = 0; m < 4; ++m) {
    const int row0 = mt + wm + m * 16 + kg * 4;
#pragma unroll
    for (int n = 0; n < 4; ++n) {
      const int col = nt + wn + n * 16 + r16;
#pragma unroll
      for (int r = 0; r < 4; ++r)
        store_c(&C[(size_t)(row0 + r) * N + col], acc[m][n][r]);
    }
  }
}

// ---------------- GEMM + fused feature map ----------------
// Same main loop; epilogue bounces C tile through LDS (bf16), then each thread
// owns one (row, head-in-tile) pair: computes 16 omega-dots, exp, normalize,
// writes xp_t[(b*H+h)*L + l][f]. No qh/kh HBM round-trip.
#define CPAD 136
__global__ __launch_bounds__(256) void gemm_feat(const unsigned short* __restrict__ A,
                                                 const unsigned short* __restrict__ Bt,
                                                 const float* __restrict__ omega,
                                                 float* __restrict__ xp_t) {
  constexpr int K = DMODEL;
  __shared__ char smem[128 * CPAD * 2 + NBF * DKH * 4];  // 34816 + 4096
  unsigned short* As = (unsigned short*)smem;            // 8KB  (main loop)
  unsigned short* Bs = (unsigned short*)(smem + 8192);   // 8KB  (main loop)
  unsigned short* Cs = (unsigned short*)smem;            // 34816B (epilogue, aliases As/Bs)
  float* om_s = (float*)(smem + 128 * CPAD * 2);         // 4KB, disjoint from As/Bs and Cs

  const int tid  = threadIdx.x;
  const int wave = tid >> 6, lane = tid & 63;
  const int mt = blockIdx.y << 7, nt = blockIdx.x << 7;
  const int wm = (wave >> 1) << 6, wn = (wave & 1) << 6;
  const int r16 = lane & 15, kg = lane >> 4;

  for (int i = tid; i < NBF * DKH; i += 256) om_s[i] = omega[i];

  floatx4 acc[4][4];
#pragma unroll
  for (int m = 0; m < 4; ++m)
#pragma unroll
    for (int n = 0; n < 4; ++n) acc[m][n] = floatx4{0.f, 0.f, 0.f, 0.f};

  const int ldrow = wave * 16 + (lane >> 2);
  const int ldcol = (lane & 3) << 3;
  const unsigned short* aG = A  + (size_t)(mt + ldrow) * K + ldcol;
  const unsigned short* bG = Bt + (size_t)(nt + ldrow) * K + ldcol;
  char* aL = (char*)As + wave * 1024;
  char* bL = (char*)Bs + wave * 1024;

  for (int kt = 0; kt < K; kt += 32) {
    __builtin_amdgcn_global_load_lds((const __attribute__((address_space(1))) void*)(aG + kt),
                                     (__attribute__((address_space(3))) void*)aL, 16, 0, 0);
    __builtin_amdgcn_global_load_lds((const __attribute__((address_space(1))) void*)(aG + (size_t)64 * K + kt),
                                     (__attribute__((address_space(3))) void*)(aL + 4096), 16, 0, 0);
    __builtin_amdgcn_global_load_lds((const __attribute__((address_space(1))) void*)(bG + kt),
                                     (__attribute__((address_space(3))) void*)bL, 16, 0, 0);
    __builtin_amdgcn_global_load_lds((const __attribute__((address_space(1))) void*)(bG + (size_t)64 * K + kt),
                                     (__attribute__((address_space(3))) void*)(bL + 4096), 16, 0, 0);
    __syncthreads();

    bf16x8 af[4], bfr[4];
#pragma unroll
    for (int m = 0; m < 4; ++m)
      af[m] = *(const bf16x8*)&As[(wm + m * 16 + r16) * 32 + kg * 8];
#pragma unroll
    for (int n = 0; n < 4; ++n)
      bfr[n] = *(const bf16x8*)&Bs[(wn + n * 16 + r16) * 32 + kg * 8];
#pragma unroll
    for (int m = 0; m < 4; ++m)
#pragma unroll
      for (int n = 0; n < 4; ++n)
        acc[m][n] = __builtin_amdgcn_mfma_f32_16x16x32_bf16(af[m], bfr[n], acc[m][n], 0, 0, 0);
    __syncthreads();
  }

  // epilogue: acc -> Cs (bf16); As/Bs dead after last barrier above
#pragma unroll
  for (int m = 0; m < 4; ++m) {
    const int row0 = wm + m * 16 + kg * 4;
#pragma unroll
    for (int n = 0; n < 4; ++n) {
      const int col = wn + n * 16 + r16;
#pragma unroll
      for (int r = 0; r < 4; ++r)
        Cs[(row0 + r) * CPAD + col] = f2bf(acc[m][n][r]);
    }
  }
  __syncthreads();

  // feature: thread -> (row, head-in-tile)
  const int row = tid >> 1, hh = tid & 1;
  const unsigned short* cr = &Cs[row * CPAD + hh * DKH];
  float x[DKH];
#pragma unroll
  for (int j = 0; j < 8; ++j) {
    ushort8v u = *(const ushort8v*)(cr + 8 * j);
#pragma unroll
    for (int t = 0; t < 8; ++t) x[8 * j + t] = bf2f(u[t]);
  }
  float p[NBF], s = 0.f;
#pragma unroll
  for (int f = 0; f < NBF; ++f) {
    const float* om = &om_s[f * DKH];
    float t = 0.f;
#pragma unroll
    for (int d = 0; d < DKH; ++d) t += x[d] * om[d];
    float pv = __expf(-0.5f * t * t);
    p[f] = pv; s += pv;
  }
  const float inv = 1.f / (s + EPSF);
  const int grow = mt + row;                 // global row = b*L + l
  const int b = grow >> 12, l = grow & 4095;
  const int hglob = (nt >> 6) + hh;
  float* outp = xp_t + (((size_t)(b * HEADS + hglob)) * L_SEQ + l) * NBF;
#pragma unroll
  for (int j = 0; j < 4; ++j) {
    float4 o;
    o.x = p[4 * j + 0] * inv; o.y = p[4 * j + 1] * inv;
    o.z = p[4 * j + 2] * inv; o.w = p[4 * j + 3] * inv;
    ((float4*)outp)[j] = o;
  }
}

// ---------------- scan phase A: per-chunk local sums ----------------
__global__ __launch_bounds__(64) void scan_chunk_sum(const float* __restrict__ kp_t,
                                                     const unsigned short* __restrict__ vh,
                                                     float* __restrict__ Sws) {
  const int c = blockIdx.x & (NCHUNK - 1);
  const int chain = blockIdx.x >> 6;
  const int b = chain >> 4, h = chain & 15;
  const int d = threadIdx.x;
  __shared__ float kp_s[CHUNK * NBF];
  const float* kpB = kp_t + ((size_t)chain * L_SEQ + c * CHUNK) * NBF;
  for (int i = 0; i < 16; ++i) kp_s[d + i * 64] = kpB[d + i * 64];
  __syncthreads();
  float S[NBF];
#pragma unroll
  for (int f = 0; f < NBF; ++f) S[f] = 0.f;
  const unsigned short* vB = vh + ((size_t)(b * L_SEQ + c * CHUNK)) * DMODEL + h * DKH + d;
  for (int l = 0; l < CHUNK; ++l) {
    float vv = bf2f(vB[(size_t)l * DMODEL]);
#pragma unroll
    for (int f = 0; f < NBF; ++f) S[f] += kp_s[l * NBF + f] * vv;
  }
  float* out = Sws + ((size_t)chain * NCHUNK + c) * STATE_SZ;
#pragma unroll
  for (int f = 0; f < NBF; ++f) out[f * 64 + d] = S[f];
  if (d < NBF) {
    float ks = 0.f;
    for (int l = 0; l < CHUNK; ++l) ks += kp_s[l * NBF + d];
    out[1024 + d] = ks;
  }
}

// ---------------- scan phase B: exclusive scan over chunks (parallel over e) ----------------
__global__ __launch_bounds__(64) void scan_chunks(float* __restrict__ Sws) {
  const int chain = blockIdx.x;
  const int e = blockIdx.y * 64 + threadIdx.x;
  if (e >= STATE_SZ) return;
  float acc = 0.f;
  float* p = Sws + (size_t)chain * NCHUNK * STATE_SZ + e;
  for (int c = 0; c < NCHUNK; ++c) {
    float v = p[(size_t)c * STATE_SZ];
    p[(size_t)c * STATE_SZ] = acc;
    acc += v;
  }
}

// ---------------- scan phase C: apply within chunk, write attn out (bf16) ----------------
__global__ __launch_bounds__(64) void scan_apply(const float* __restrict__ qp_t,
                                                 const float* __restrict__ kp_t,
                                                 const unsigned short* __restrict__ vh,
                                                 const float* __restrict__ Sws,
                                                 unsigned short* __restrict__ attn) {
  const int c = blockIdx.x & (NCHUNK - 1);
  const int chain = blockIdx.x >> 6;
  const int b = chain >> 4, h = chain & 15;
  const int d = threadIdx.x;
  __shared__ float kp_s[CHUNK * NBF];
  __shared__ float qp_s[CHUNK * NBF];
  {
    const float* kpB = kp_t + ((size_t)chain * L_SEQ + c * CHUNK) * NBF;
    const float* qpB = qp_t + ((size_t)chain * L_SEQ + c * CHUNK) * NBF;
    for (int i = 0; i < 16; ++i) {
      kp_s[d + i * 64] = kpB[d + i * 64];
      qp_s[d + i * 64] = qpB[d + i * 64];
    }
  }
  __syncthreads();
  const float* st = Sws + ((size_t)chain * NCHUNK + c) * STATE_SZ;
  float S[NBF], kc[NBF];
#pragma unroll
  for (int f = 0; f < NBF; ++f) S[f] = st[f * 64 + d];
#pragma unroll
  for (int f = 0; f < NBF; ++f) kc[f] = st[1024 + f];
  const unsigned short* vB = vh + ((size_t)(b * L_SEQ + c * CHUNK)) * DMODEL + h * DKH + d;
  unsigned short* oB = attn + ((size_t)(b * L_SEQ + c * CHUNK)) * DMODEL + h * DKH + d;
  for (int l = 0; l < CHUNK; ++l) {
    float vv = bf2f(vB[(size_t)l * DMODEL]);
    float num = 0.f, den = 0.f;
#pragma unroll
    for (int f = 0; f < NBF; ++f) {
      float kpf = kp_s[l * NBF + f];
      S[f]  += kpf * vv;
      kc[f] += kpf;
      float qpf = qp_s[l * NBF + f];
      num += qpf * S[f];
      den += qpf * kc[f];
    }
    oB[(size_t)l * DMODEL] = f2bf(num / (den + EPSF));
  }
}

// ---------------- host launch ----------------
extern "C" void kernel_launch(void* const* d_in, const int* in_sizes, int n_in,
                              void* d_out, int out_size, void* d_ws, size_t ws_size,
                              hipStream_t stream) {
  const float* q   = (const float*)d_in[0];
  const float* k   = (const float*)d_in[1];
  const float* v   = (const float*)d_in[2];
  const float* w_q = (const float*)d_in[3];
  const float* w_k = (const float*)d_in[4];
  const float* w_v = (const float*)d_in[5];
  const float* w_o = (const float*)d_in[6];
  const float* omega = (const float*)d_in[7];
  float* out = (float*)d_out;

  constexpr size_t NQ = (size_t)BATCH * L_SEQ * DMODEL;      // 8388608
  constexpr size_t NW = (size_t)DMODEL * DMODEL;             // 1048576
  constexpr size_t NP = (size_t)BATCH * HEADS * L_SEQ * NBF; // 2097152
  constexpr size_t NS = (size_t)NCHAIN * NCHUNK * STATE_SZ;

  char* ws = (char*)d_ws;
  size_t off = 0;
  auto alc = [&](size_t bytes) { void* p = ws + off; off += (bytes + 255) & ~(size_t)255; return p; };
  unsigned short* qb  = (unsigned short*)alc(NQ * 2);
  unsigned short* kb  = (unsigned short*)alc(NQ * 2);
  unsigned short* vb  = (unsigned short*)alc(NQ * 2);
  unsigned short* wqb = (unsigned short*)alc(NW * 2);
  unsigned short* wkb = (unsigned short*)alc(NW * 2);
  unsigned short* wvb = (unsigned short*)alc(NW * 2);
  unsigned short* wob = (unsigned short*)alc(NW * 2);
  unsigned short* vh  = (unsigned short*)alc(NQ * 2);
  float* qp  = (float*)alc(NP * 4);
  float* kp  = (float*)alc(NP * 4);
  float* Sws = (float*)alc(NS * 4);
  unsigned short* attn = qb;  // qb dead after q projection

  cast3<<<dim3((int)(NQ / 4 / 256), 3), 256, 0, stream>>>(q, k, v, qb, kb, vb, (int)(NQ / 4));
  cast4<<<dim3((int)(NW / 4 / 256), 4), 256, 0, stream>>>(w_q, w_k, w_v, w_o, wqb, wkb, wvb, wob, (int)(NW / 4));

  dim3 gg(DMODEL / 128, (BATCH * L_SEQ) / 128);  // (8, 64)

  gemm_feat<<<gg, 256, 0, stream>>>(qb, wqb, omega, qp);
  gemm_feat<<<gg, 256, 0, stream>>>(kb, wkb, omega, kp);
  gemm_bt<unsigned short><<<gg, 256, 0, stream>>>(vb, wvb, vh, BATCH * L_SEQ, DMODEL, DMODEL);

  scan_chunk_sum<<<NCHAIN * NCHUNK, 64, 0, stream>>>(kp, vh, Sws);
  scan_chunks<<<dim3(NCHAIN, (STATE_SZ + 63) / 64), 64, 0, stream>>>(Sws);
  scan_apply<<<NCHAIN * NCHUNK, 64, 0, stream>>>(qp, kp, vh, Sws, attn);

  gemm_bt<float><<<gg, 256, 0, stream>>>(attn, wob, out, BATCH * L_SEQ, DMODEL, DMODEL);
}

// Round 3
// 183.578 us; speedup vs baseline: 1.4496x; 1.1523x over previous
//
#include <hip/hip_runtime.h>

#define L_SEQ   4096
#define BATCH   2
#define DMODEL  1024
#define HEADS   16
#define DKH     64
#define NBF     16
#define CHUNK   64
#define NCHUNK  64          // L_SEQ / CHUNK
#define NCHAIN  32          // BATCH * HEADS
#define STATE_SZ 1040       // NBF*DKH + NBF
#define EPSF    1e-6f

typedef __attribute__((ext_vector_type(8))) __bf16 bf16x8;
typedef __attribute__((ext_vector_type(4))) float  floatx4;

__device__ __forceinline__ unsigned short f2bf(float x) {
  unsigned u = __builtin_bit_cast(unsigned, x);
  u += 0x7fffu + ((u >> 16) & 1u);
  return (unsigned short)(u >> 16);
}
__device__ __forceinline__ float bf2f(unsigned short u) {
  return __builtin_bit_cast(float, ((unsigned)u) << 16);
}

// ---------------- casts f32 -> bf16 ----------------
__global__ __launch_bounds__(256) void cast3(const float* __restrict__ a, const float* __restrict__ b,
                                             const float* __restrict__ c,
                                             unsigned short* __restrict__ oa, unsigned short* __restrict__ ob,
                                             unsigned short* __restrict__ oc, int n4) {
  int i = blockIdx.x * 256 + threadIdx.x;
  if (i >= n4) return;
  int w = blockIdx.y;
  const float* in = (w == 0) ? a : (w == 1) ? b : c;
  unsigned short* out = (w == 0) ? oa : (w == 1) ? ob : oc;
  float4 v = ((const float4*)in)[i];
  ushort4 o;
  o.x = f2bf(v.x); o.y = f2bf(v.y); o.z = f2bf(v.z); o.w = f2bf(v.w);
  ((ushort4*)out)[i] = o;
}

__global__ __launch_bounds__(256) void cast2(const float* __restrict__ a, const float* __restrict__ b,
                                             unsigned short* __restrict__ oa, unsigned short* __restrict__ ob,
                                             int n4) {
  int i = blockIdx.x * 256 + threadIdx.x;
  if (i >= n4) return;
  const float* in = blockIdx.y ? b : a;
  unsigned short* out = blockIdx.y ? ob : oa;
  float4 v = ((const float4*)in)[i];
  ushort4 o;
  o.x = f2bf(v.x); o.y = f2bf(v.y); o.z = f2bf(v.z); o.w = f2bf(v.w);
  ((ushort4*)out)[i] = o;
}

// ---------------- combine: Wt[h*16+f, :] = sum_d omega[f,d] * w[h*64+d, :] (bf16 out) ----------------
__global__ __launch_bounds__(256) void combine_w(const float* __restrict__ wq, const float* __restrict__ wk,
                                                 const float* __restrict__ omega,
                                                 unsigned short* __restrict__ wtq,
                                                 unsigned short* __restrict__ wtk) {
  const int s = blockIdx.x;   // 64-col slab, 0..15
  const int h = blockIdx.y;   // head
  const float* w = blockIdx.z ? wk : wq;
  unsigned short* wt = blockIdx.z ? wtk : wtq;
  __shared__ float ws[64 * 64];
  __shared__ float oms[NBF * 64];
  const int tid = threadIdx.x;
  for (int i = tid; i < 64 * 64; i += 256) {
    int r = i >> 6, c = i & 63;
    ws[i] = w[(size_t)(h * 64 + r) * DMODEL + s * 64 + c];
  }
  for (int i = tid; i < NBF * 64; i += 256) oms[i] = omega[i];
  __syncthreads();
  for (int j = tid; j < NBF * 64; j += 256) {
    int f = j >> 6, c = j & 63;
    float acc = 0.f;
#pragma unroll
    for (int d = 0; d < 64; ++d) acc += oms[f * 64 + d] * ws[d * 64 + c];
    wt[(size_t)(h * NBF + f) * DMODEL + s * 64 + c] = f2bf(acc);
  }
}

// ---------------- bf16 MFMA GEMM: C = A(MxK) * Bt(NxK)^T ----------------
__device__ __forceinline__ void store_c(float* p, float v) { *p = v; }
__device__ __forceinline__ void store_c(unsigned short* p, float v) { *p = f2bf(v); }

template <typename OutT>
__global__ __launch_bounds__(256) void gemm_bt(const unsigned short* __restrict__ A,
                                               const unsigned short* __restrict__ Bt,
                                               OutT* __restrict__ C,
                                               int M, int N, int K) {
  __shared__ unsigned short As[128 * 32];
  __shared__ unsigned short Bs[128 * 32];
  const int tid  = threadIdx.x;
  const int wave = tid >> 6, lane = tid & 63;
  const int mt = blockIdx.y << 7, nt = blockIdx.x << 7;
  const int wm = (wave >> 1) << 6, wn = (wave & 1) << 6;
  const int r16 = lane & 15, kg = lane >> 4;

  floatx4 acc[4][4];
#pragma unroll
  for (int m = 0; m < 4; ++m)
#pragma unroll
    for (int n = 0; n < 4; ++n) acc[m][n] = floatx4{0.f, 0.f, 0.f, 0.f};

  const int ldrow = wave * 16 + (lane >> 2);
  const int ldcol = (lane & 3) << 3;
  const unsigned short* aG = A  + (size_t)(mt + ldrow) * K + ldcol;
  const unsigned short* bG = Bt + (size_t)(nt + ldrow) * K + ldcol;
  char* aL = (char*)As + wave * 1024;
  char* bL = (char*)Bs + wave * 1024;

  for (int kt = 0; kt < K; kt += 32) {
    __builtin_amdgcn_global_load_lds((const __attribute__((address_space(1))) void*)(aG + kt),
                                     (__attribute__((address_space(3))) void*)aL, 16, 0, 0);
    __builtin_amdgcn_global_load_lds((const __attribute__((address_space(1))) void*)(aG + (size_t)64 * K + kt),
                                     (__attribute__((address_space(3))) void*)(aL + 4096), 16, 0, 0);
    __builtin_amdgcn_global_load_lds((const __attribute__((address_space(1))) void*)(bG + kt),
                                     (__attribute__((address_space(3))) void*)bL, 16, 0, 0);
    __builtin_amdgcn_global_load_lds((const __attribute__((address_space(1))) void*)(bG + (size_t)64 * K + kt),
                                     (__attribute__((address_space(3))) void*)(bL + 4096), 16, 0, 0);
    __syncthreads();

    bf16x8 af[4], bfr[4];
#pragma unroll
    for (int m = 0; m < 4; ++m)
      af[m] = *(const bf16x8*)&As[(wm + m * 16 + r16) * 32 + kg * 8];
#pragma unroll
    for (int n = 0; n < 4; ++n)
      bfr[n] = *(const bf16x8*)&Bs[(wn + n * 16 + r16) * 32 + kg * 8];
#pragma unroll
    for (int m = 0; m < 4; ++m)
#pragma unroll
      for (int n = 0; n < 4; ++n)
        acc[m][n] = __builtin_amdgcn_mfma_f32_16x16x32_bf16(af[m], bfr[n], acc[m][n], 0, 0, 0);
    __syncthreads();
  }

#pragma unroll
  for (int m = 0; m < 4; ++m) {
    const int row0 = mt + wm + m * 16 + kg * 4;
#pragma unroll
    for (int n = 0; n < 4; ++n) {
      const int col = nt + wn + n * 16 + r16;
#pragma unroll
      for (int r = 0; r < 4; ++r)
        store_c(&C[(size_t)(row0 + r) * N + col], acc[m][n][r]);
    }
  }
}

// ---------------- qk GEMM (N=256) with fused in-register feature map ----------------
// C[row, h*16+f] = A(row,:) . Wt(h*16+f,:); p = exp(-0.5 C^2), normalized over the
// 16 features f, which for fixed (m,n,r) live in the 16 lanes r16=0..15.
// Writes xp_t[((b*H+h)*L + l)*16 + f]  (f32).
__global__ __launch_bounds__(256) void gemm_qk_feat(const unsigned short* __restrict__ qb,
                                                    const unsigned short* __restrict__ kb,
                                                    const unsigned short* __restrict__ wtq,
                                                    const unsigned short* __restrict__ wtk,
                                                    float* __restrict__ qp_t,
                                                    float* __restrict__ kp_t) {
  constexpr int K = DMODEL;
  const unsigned short* A  = blockIdx.z ? kb : qb;
  const unsigned short* Bt = blockIdx.z ? wtk : wtq;
  float* xp_t = blockIdx.z ? kp_t : qp_t;

  __shared__ unsigned short As[128 * 32];
  __shared__ unsigned short Bs[128 * 32];
  const int tid  = threadIdx.x;
  const int wave = tid >> 6, lane = tid & 63;
  const int mt = blockIdx.y << 7, nt = blockIdx.x << 7;
  const int wm = (wave >> 1) << 6, wn = (wave & 1) << 6;
  const int r16 = lane & 15, kg = lane >> 4;

  floatx4 acc[4][4];
#pragma unroll
  for (int m = 0; m < 4; ++m)
#pragma unroll
    for (int n = 0; n < 4; ++n) acc[m][n] = floatx4{0.f, 0.f, 0.f, 0.f};

  const int ldrow = wave * 16 + (lane >> 2);
  const int ldcol = (lane & 3) << 3;
  const unsigned short* aG = A  + (size_t)(mt + ldrow) * K + ldcol;
  const unsigned short* bG = Bt + (size_t)(nt + ldrow) * K + ldcol;
  char* aL = (char*)As + wave * 1024;
  char* bL = (char*)Bs + wave * 1024;

  for (int kt = 0; kt < K; kt += 32) {
    __builtin_amdgcn_global_load_lds((const __attribute__((address_space(1))) void*)(aG + kt),
                                     (__attribute__((address_space(3))) void*)aL, 16, 0, 0);
    __builtin_amdgcn_global_load_lds((const __attribute__((address_space(1))) void*)(aG + (size_t)64 * K + kt),
                                     (__attribute__((address_space(3))) void*)(aL + 4096), 16, 0, 0);
    __builtin_amdgcn_global_load_lds((const __attribute__((address_space(1))) void*)(bG + kt),
                                     (__attribute__((address_space(3))) void*)bL, 16, 0, 0);
    __builtin_amdgcn_global_load_lds((const __attribute__((address_space(1))) void*)(bG + (size_t)64 * K + kt),
                                     (__attribute__((address_space(3))) void*)(bL + 4096), 16, 0, 0);
    __syncthreads();

    bf16x8 af[4], bfr[4];
#pragma unroll
    for (int m = 0; m < 4; ++m)
      af[m] = *(const bf16x8*)&As[(wm + m * 16 + r16) * 32 + kg * 8];
#pragma unroll
    for (int n = 0; n < 4; ++n)
      bfr[n] = *(const bf16x8*)&Bs[(wn + n * 16 + r16) * 32 + kg * 8];
#pragma unroll
    for (int m = 0; m < 4; ++m)
#pragma unroll
      for (int n = 0; n < 4; ++n)
        acc[m][n] = __builtin_amdgcn_mfma_f32_16x16x32_bf16(af[m], bfr[n], acc[m][n], 0, 0, 0);
    __syncthreads();
  }

  const int hbase = (nt + wn) >> 4;
#pragma unroll
  for (int m = 0; m < 4; ++m) {
#pragma unroll
    for (int n = 0; n < 4; ++n) {
      const int hglob = hbase + n;
#pragma unroll
      for (int r = 0; r < 4; ++r) {
        float x = acc[m][n][r];
        float p = __expf(-0.5f * x * x);
        float s = p;
        s += __shfl_xor(s, 1);
        s += __shfl_xor(s, 2);
        s += __shfl_xor(s, 4);
        s += __shfl_xor(s, 8);
        float o = p / (s + EPSF);
        const int row = mt + wm + m * 16 + kg * 4 + r;
        const int b = row >> 12, l = row & 4095;
        xp_t[(((size_t)(b * HEADS + hglob)) * L_SEQ + l) * NBF + r16] = o;
      }
    }
  }
}

// ---------------- scan phase A: per-chunk local sums ----------------
__global__ __launch_bounds__(64) void scan_chunk_sum(const float* __restrict__ kp_t,
                                                     const unsigned short* __restrict__ vh,
                                                     float* __restrict__ Sws) {
  const int c = blockIdx.x & (NCHUNK - 1);
  const int chain = blockIdx.x >> 6;
  const int b = chain >> 4, h = chain & 15;
  const int d = threadIdx.x;
  __shared__ float kp_s[CHUNK * NBF];
  const float* kpB = kp_t + ((size_t)chain * L_SEQ + c * CHUNK) * NBF;
  for (int i = 0; i < 16; ++i) kp_s[d + i * 64] = kpB[d + i * 64];
  __syncthreads();
  float S[NBF];
#pragma unroll
  for (int f = 0; f < NBF; ++f) S[f] = 0.f;
  const unsigned short* vB = vh + ((size_t)(b * L_SEQ + c * CHUNK)) * DMODEL + h * DKH + d;
  for (int l = 0; l < CHUNK; ++l) {
    float vv = bf2f(vB[(size_t)l * DMODEL]);
#pragma unroll
    for (int f = 0; f < NBF; ++f) S[f] += kp_s[l * NBF + f] * vv;
  }
  float* out = Sws + ((size_t)chain * NCHUNK + c) * STATE_SZ;
#pragma unroll
  for (int f = 0; f < NBF; ++f) out[f * 64 + d] = S[f];
  if (d < NBF) {
    float ks = 0.f;
    for (int l = 0; l < CHUNK; ++l) ks += kp_s[l * NBF + d];
    out[1024 + d] = ks;
  }
}

// ---------------- scan phase B: exclusive scan over chunks (parallel over e) ----------------
__global__ __launch_bounds__(64) void scan_chunks(float* __restrict__ Sws) {
  const int chain = blockIdx.x;
  const int e = blockIdx.y * 64 + threadIdx.x;
  if (e >= STATE_SZ) return;
  float acc = 0.f;
  float* p = Sws + (size_t)chain * NCHUNK * STATE_SZ + e;
  for (int c = 0; c < NCHUNK; ++c) {
    float v = p[(size_t)c * STATE_SZ];
    p[(size_t)c * STATE_SZ] = acc;
    acc += v;
  }
}

// ---------------- scan phase C: apply within chunk, write attn (bf16) ----------------
__global__ __launch_bounds__(64) void scan_apply(const float* __restrict__ qp_t,
                                                 const float* __restrict__ kp_t,
                                                 const unsigned short* __restrict__ vh,
                                                 const float* __restrict__ Sws,
                                                 unsigned short* __restrict__ attn) {
  const int c = blockIdx.x & (NCHUNK - 1);
  const int chain = blockIdx.x >> 6;
  const int b = chain >> 4, h = chain & 15;
  const int d = threadIdx.x;
  __shared__ float kp_s[CHUNK * NBF];
  __shared__ float qp_s[CHUNK * NBF];
  {
    const float* kpB = kp_t + ((size_t)chain * L_SEQ + c * CHUNK) * NBF;
    const float* qpB = qp_t + ((size_t)chain * L_SEQ + c * CHUNK) * NBF;
    for (int i = 0; i < 16; ++i) {
      kp_s[d + i * 64] = kpB[d + i * 64];
      qp_s[d + i * 64] = qpB[d + i * 64];
    }
  }
  __syncthreads();
  const float* st = Sws + ((size_t)chain * NCHUNK + c) * STATE_SZ;
  float S[NBF], kc[NBF];
#pragma unroll
  for (int f = 0; f < NBF; ++f) S[f] = st[f * 64 + d];
#pragma unroll
  for (int f = 0; f < NBF; ++f) kc[f] = st[1024 + f];
  const unsigned short* vB = vh + ((size_t)(b * L_SEQ + c * CHUNK)) * DMODEL + h * DKH + d;
  unsigned short* oB = attn + ((size_t)(b * L_SEQ + c * CHUNK)) * DMODEL + h * DKH + d;
  for (int l = 0; l < CHUNK; ++l) {
    float vv = bf2f(vB[(size_t)l * DMODEL]);
    float num = 0.f, den = 0.f;
#pragma unroll
    for (int f = 0; f < NBF; ++f) {
      float kpf = kp_s[l * NBF + f];
      S[f]  += kpf * vv;
      kc[f] += kpf;
      float qpf = qp_s[l * NBF + f];
      num += qpf * S[f];
      den += qpf * kc[f];
    }
    oB[(size_t)l * DMODEL] = f2bf(num / (den + EPSF));
  }
}

// ---------------- host launch ----------------
extern "C" void kernel_launch(void* const* d_in, const int* in_sizes, int n_in,
                              void* d_out, int out_size, void* d_ws, size_t ws_size,
                              hipStream_t stream) {
  const float* q   = (const float*)d_in[0];
  const float* k   = (const float*)d_in[1];
  const float* v   = (const float*)d_in[2];
  const float* w_q = (const float*)d_in[3];
  const float* w_k = (const float*)d_in[4];
  const float* w_v = (const float*)d_in[5];
  const float* w_o = (const float*)d_in[6];
  const float* omega = (const float*)d_in[7];
  float* out = (float*)d_out;

  constexpr size_t NQ = (size_t)BATCH * L_SEQ * DMODEL;      // 8388608
  constexpr size_t NW = (size_t)DMODEL * DMODEL;             // 1048576
  constexpr size_t NWT = (size_t)HEADS * NBF * DMODEL;       // 262144
  constexpr size_t NP = (size_t)BATCH * HEADS * L_SEQ * NBF; // 2097152
  constexpr size_t NS = (size_t)NCHAIN * NCHUNK * STATE_SZ;

  char* ws = (char*)d_ws;
  size_t off = 0;
  auto alc = [&](size_t bytes) { void* p = ws + off; off += (bytes + 255) & ~(size_t)255; return p; };
  unsigned short* qb  = (unsigned short*)alc(NQ * 2);
  unsigned short* kb  = (unsigned short*)alc(NQ * 2);
  unsigned short* vb  = (unsigned short*)alc(NQ * 2);
  unsigned short* wvb = (unsigned short*)alc(NW * 2);
  unsigned short* wob = (unsigned short*)alc(NW * 2);
  unsigned short* wtq = (unsigned short*)alc(NWT * 2);
  unsigned short* wtk = (unsigned short*)alc(NWT * 2);
  unsigned short* vh  = (unsigned short*)alc(NQ * 2);
  float* qp  = (float*)alc(NP * 4);
  float* kp  = (float*)alc(NP * 4);
  float* Sws = (float*)alc(NS * 4);
  unsigned short* attn = qb;  // qb dead after qk GEMM

  combine_w<<<dim3(16, 16, 2), 256, 0, stream>>>(w_q, w_k, omega, wtq, wtk);
  cast3<<<dim3((int)(NQ / 4 / 256), 3), 256, 0, stream>>>(q, k, v, qb, kb, vb, (int)(NQ / 4));
  cast2<<<dim3((int)(NW / 4 / 256), 2), 256, 0, stream>>>(w_v, w_o, wvb, wob, (int)(NW / 4));

  gemm_qk_feat<<<dim3(2, 64, 2), 256, 0, stream>>>(qb, kb, wtq, wtk, qp, kp);
  gemm_bt<unsigned short><<<dim3(8, 64), 256, 0, stream>>>(vb, wvb, vh, BATCH * L_SEQ, DMODEL, DMODEL);

  scan_chunk_sum<<<NCHAIN * NCHUNK, 64, 0, stream>>>(kp, vh, Sws);
  scan_chunks<<<dim3(NCHAIN, (STATE_SZ + 63) / 64), 64, 0, stream>>>(Sws);
  scan_apply<<<NCHAIN * NCHUNK, 64, 0, stream>>>(qp, kp, vh, Sws, attn);

  gemm_bt<float><<<dim3(8, 64), 256, 0, stream>>>(attn, wob, out, BATCH * L_SEQ, DMODEL, DMODEL);
}